// Round 3
// baseline (1626.492 us; speedup 1.0000x reference)
//
#include <hip/hip_runtime.h>
#include <math.h>

#define NPOS 8192
#define MAXIT 50
#define TOLF 1e-9f
#define RAD  2544            // w(2544)=exp(-19.3)=4.2e-9; tail mass ~3e-7 relative
#define PADJ 2560
#define EUW  13312           // padded plane length: 8192 + 2*2560 = 13312
#define EUSZ (EUW * 8)       // 106496 floats per eu buffer (8 planes)

// ws layout (float offsets)
#define OFF_W2   0           // 16384: w2[d+8191] = exp(K(|d|))
#define OFF_LA   16384       // 65536: log(alpha)
#define OFF_F    81920       // 65536: potential f
#define OFF_CB   147456      // 8: fixed per-batch stabilizer cb = max(la)
#define OFF_SLOT 147464      // 800 uints: gap slots
#define OFF_EU   148480      // 2 * 106496: eu double buffer, scalar planes [b][j']

#define SLOT_DMAX 0          // 50*8
#define SLOT_DMIN 400        // 50*8

__device__ inline unsigned fkey(float x) {
  unsigned b = __float_as_uint(x);
  return (b & 0x80000000u) ? ~b : (b | 0x80000000u);
}
__device__ inline float fval(unsigned k) {
  unsigned b = (k & 0x80000000u) ? (k ^ 0x80000000u) : ~k;
  return __uint_as_float(b);
}

// run body k iff gap_{k-1} >= TOL (never-run slots -> -inf -> stay stopped)
__device__ inline bool run_iter(const unsigned* slots, int k) {
  if (k == 0) return true;
  const unsigned* dmax = slots + SLOT_DMAX + (k - 1) * 8;
  const unsigned* dmin = slots + SLOT_DMIN + (k - 1) * 8;
  float s = 0.f;
#pragma unroll
  for (int b = 0; b < 8; ++b) s += fval(dmax[b]) - fval(dmin[b]);
  return (s * 0.125f) >= TOLF;
}

__global__ __launch_bounds__(256) void setup_a(const float* __restrict__ alpha,
                                               const float* __restrict__ kern,
                                               float* __restrict__ ws) {
  int id = blockIdx.x * 256 + threadIdx.x;        // grid 832 -> 212992 threads
  if (id < 2 * EUSZ) ws[OFF_EU + id] = 0.f;       // zero both eu buffers
  if (id < 16384) {
    int d = id - 8191; if (d < 0) d = -d; if (d > 8191) d = 8191;
    ws[OFF_W2 + id] = expf(kern[d]);              // kernel row 0; Toeplitz-exact
  }
  if (id < 65536) {
    float a = alpha[id];
    ws[OFF_LA + id] = (a > 0.f) ? logf(a) : -INFINITY;
    ws[OFF_F + id] = 0.f;
  }
  unsigned* slots = (unsigned*)(ws + OFF_SLOT);
  if (id < 400) {
    slots[SLOT_DMAX + id] = fkey(-INFINITY);
    slots[SLOT_DMIN + id] = fkey(INFINITY);
  }
}

__global__ __launch_bounds__(256) void setup_cb(float* __restrict__ ws) {
  int b = blockIdx.x;
  const float* lap = ws + OFF_LA + b * NPOS;
  float m = -INFINITY;
  for (int i = threadIdx.x; i < NPOS; i += 256) m = fmaxf(m, lap[i]);
#pragma unroll
  for (int o = 1; o < 64; o <<= 1) m = fmaxf(m, __shfl_xor(m, o, 64));
  __shared__ float r[4];
  if ((threadIdx.x & 63) == 0) r[threadIdx.x >> 6] = m;
  __syncthreads();
  if (threadIdx.x == 0)
    ws[OFF_CB + b] = fmaxf(fmaxf(r[0], r[1]), fmaxf(r[2], r[3]));
}

__global__ __launch_bounds__(256) void setup_eu(float* __restrict__ ws) {
  int id = blockIdx.x * 256 + threadIdx.x;        // grid 256 -> 65536
  int b = id >> 13, i = id & (NPOS - 1);
  float la = ws[OFF_LA + id];
  float cb = ws[OFF_CB + b];
  ws[OFF_EU + (size_t)b * EUW + i + PADJ] = expf(la - cb);
}

// ---- fused iteration ----
// grid 2048: b = blk&7, i-tile of 32 = blk>>3. 4 waves; wave w covers 1280 j
// (5 supersteps of 256); lane owns 4 consecutive j per superstep.
// jj = 1280w + 256s + 4l + sub; j = i0 - RAD + jj; covers [i0-2544, i0+2575].
__global__ __launch_bounds__(256, 4) void conv_fused(
    const float* __restrict__ w2, const float* __restrict__ la,
    float* __restrict__ f, const float* __restrict__ cb,
    unsigned* __restrict__ slots, const float* __restrict__ eu,
    float* __restrict__ eunext, int k)
{
  if (!run_iter(slots, k)) return;
  const int b  = blockIdx.x & 7;
  const int i0 = (blockIdx.x >> 3) << 5;
  const int lane = threadIdx.x & 63;
  const int wid  = threadIdx.x >> 6;

  float acc[32];
#pragma unroll
  for (int a = 0; a < 32; ++a) acc[a] = 0.f;

  // eu plane, float4 index = j'/4; j'(s=0,sub=0) = i0+16 + 1280w + 4l
  const float4* ep  = (const float4*)(eu + (size_t)b * EUW) +
                      (((i0 + 16) >> 2) + 320 * wid + lane);
  const float4* wp4 = (const float4*)w2;
  // w2 float index base = 10735 - 1280w - 256s - 4l (≡3 mod 4); wv = L[3+ii-sub]
  const int Mq = 2683 - 320 * wid - lane;         // float4 idx of (base-3) at s=0

#pragma unroll
  for (int s = 0; s < 5; ++s) {
    float4 ev = ep[s << 6];                        // 4 consecutive j (sub 0..3)
    float L[36];
#pragma unroll
    for (int q = 0; q < 9; ++q) {
      float4 t = wp4[Mq - (s << 6) + q];
      L[4*q] = t.x; L[4*q+1] = t.y; L[4*q+2] = t.z; L[4*q+3] = t.w;
    }
    const float es[4] = {ev.x, ev.y, ev.z, ev.w};
#pragma unroll
    for (int sub = 0; sub < 4; ++sub) {
      float e = es[sub];
#pragma unroll
      for (int ii = 0; ii < 32; ++ii)
        acc[ii] = fmaf(L[3 + ii - sub], e, acc[ii]);
    }
  }

  // register-halving reduce: 5 rounds within 32-lane halves, then cross-half.
  // Ends: lanes l and l+32 hold full sum of original acc index a = l (l<32).
#pragma unroll
  for (int r = 0; r < 5; ++r) {
    const int bit = (lane >> r) & 1;
#pragma unroll
    for (int m = 0; m < (16 >> r); ++m) {
      float x = bit ? acc[2 * m + 1] : acc[2 * m];
      acc[m] = x + __shfl_xor(x, 1 << r, 64);
    }
  }
  acc[0] += __shfl_xor(acc[0], 32, 64);

  __shared__ float red[4][32];
  if (lane < 32) red[wid][lane] = acc[0];
  __syncthreads();

  const int t = threadIdx.x;
  if (t < 32) {
    float v = red[0][t] + red[1][t] + red[2][t] + red[3][t];
    const int i = i0 + t;
    float cbb = cb[b];
    float g = -2.f * (logf(v) + cbb);
    float fo = f[b * NPOS + i];
    float d  = fo - g;
    float fn = 0.5f * (fo + g);
    f[b * NPOS + i] = fn;
    float un = 0.5f * fn + la[b * NPOS + i];
    eunext[(size_t)b * EUW + i + PADJ] = expf(un - cbb);
    float dmax = d, dmin = d;
#pragma unroll
    for (int o = 1; o < 32; o <<= 1) {
      dmax = fmaxf(dmax, __shfl_xor(dmax, o, 64));
      dmin = fminf(dmin, __shfl_xor(dmin, o, 64));
    }
    if (t == 0) {
      atomicMax(&slots[SLOT_DMAX + k * 8 + b], fkey(dmax));
      atomicMin(&slots[SLOT_DMIN + k * 8 + b], fkey(dmin));
    }
  }
}

__global__ __launch_bounds__(256) void value_k(const float* __restrict__ alpha,
                                               const float* __restrict__ ws,
                                               float* __restrict__ out) {
  int b = blockIdx.x;
  const float* fp = ws + OFF_F + b * NPOS;
  const float* ap = alpha + b * NPOS;
  float s = 0.f;
  for (int i = threadIdx.x; i < NPOS; i += 256) s = fmaf(fp[i], ap[i], s);
#pragma unroll
  for (int o = 1; o < 64; o <<= 1) s += __shfl_xor(s, o, 64);
  __shared__ float red[4];
  if ((threadIdx.x & 63) == 0) red[threadIdx.x >> 6] = s;
  __syncthreads();
  if (threadIdx.x == 0) out[b] = -(red[0] + red[1] + red[2] + red[3]);
}

extern "C" void kernel_launch(void* const* d_in, const int* in_sizes, int n_in,
                              void* d_out, int out_size, void* d_ws, size_t ws_size,
                              hipStream_t stream) {
  const float* alpha = (const float*)d_in[0];
  const float* kern  = (const float*)d_in[1];
  float* ws  = (float*)d_ws;
  float* out = (float*)d_out;

  float* w2p = ws + OFF_W2;
  float* lap = ws + OFF_LA;
  float* fp  = ws + OFF_F;
  float* cbp = ws + OFF_CB;
  unsigned* slots = (unsigned*)(ws + OFF_SLOT);

  setup_a<<<832, 256, 0, stream>>>(alpha, kern, ws);
  setup_cb<<<8, 256, 0, stream>>>(ws);
  setup_eu<<<256, 256, 0, stream>>>(ws);
  for (int k = 0; k < MAXIT; ++k) {
    float* ecur = ws + OFF_EU + (size_t)(k & 1) * EUSZ;
    float* enxt = ws + OFF_EU + (size_t)((k + 1) & 1) * EUSZ;
    conv_fused<<<2048, 256, 0, stream>>>(w2p, lap, fp, cbp, slots, ecur, enxt, k);
  }
  value_k<<<8, 256, 0, stream>>>(alpha, ws, out);
}

// Round 4
// 1336.373 us; speedup vs baseline: 1.2171x; 1.2171x over previous
//
#include <hip/hip_runtime.h>
#include <math.h>

#define NPOS 8192
#define MAXIT 50
#define TOLF 1e-9f
#define PADJ 2432            // window radius; w(2432)=2.2e-8 -> truncation ~1e-7 rel
#define EUW  13056           // 8192 + 2*2432
#define EUSZ (EUW * 8)       // 104448 floats per eu buffer (8 scalar planes [b][j'])
#define NCH  80              // 64-j chunks per 256-i block (window 5120 = 256+2*2432)

// ws layout (float offsets)
#define OFF_W2   0           // 16384: w2[d+8191] = exp(K(|d|))
#define OFF_LA   16384       // 65536: log(alpha)
#define OFF_F    81920       // 65536: potential f
#define OFF_CB   147456      // 8: fixed per-batch stabilizer cb = max(la)
#define OFF_SLOT 147464      // 800 uints: gap slots
#define OFF_EU   148480      // 2 * 104448: eu double buffer
#define OFF_PART 357376      // 80*8*8192 = 5242880 partial sums  (~22.4 MB total ws)

#define SLOT_DMAX 0          // 50*8
#define SLOT_DMIN 400        // 50*8

// static float4 component select (folds at compile time under #pragma unroll)
#define EC(v,kk) ((kk)==0?(v).x:(kk)==1?(v).y:(kk)==2?(v).z:(v).w)

__device__ inline unsigned fkey(float x) {
  unsigned b = __float_as_uint(x);
  return (b & 0x80000000u) ? ~b : (b | 0x80000000u);
}
__device__ inline float fval(unsigned k) {
  unsigned b = (k & 0x80000000u) ? (k ^ 0x80000000u) : ~k;
  return __uint_as_float(b);
}

// run body k iff gap_{k-1} >= TOL (never-run slots -> -inf -> stay stopped)
__device__ inline bool run_iter(const unsigned* slots, int k) {
  if (k == 0) return true;
  const unsigned* dmax = slots + SLOT_DMAX + (k - 1) * 8;
  const unsigned* dmin = slots + SLOT_DMIN + (k - 1) * 8;
  float s = 0.f;
#pragma unroll
  for (int b = 0; b < 8; ++b) s += fval(dmax[b]) - fval(dmin[b]);
  return (s * 0.125f) >= TOLF;
}

__global__ __launch_bounds__(256) void setup_a(const float* __restrict__ alpha,
                                               const float* __restrict__ kern,
                                               float* __restrict__ ws) {
  int id = blockIdx.x * 256 + threadIdx.x;        // grid 816 -> 208896 threads
  ws[OFF_EU + id] = 0.f;                          // zero both eu buffers (2*104448)
  if (id < 16384) {
    int d = id - 8191; if (d < 0) d = -d; if (d > 8191) d = 8191;
    ws[OFF_W2 + id] = expf(kern[d]);              // kernel row 0; Toeplitz-exact
  }
  if (id < 65536) {
    float a = alpha[id];
    ws[OFF_LA + id] = (a > 0.f) ? logf(a) : -INFINITY;
    ws[OFF_F + id] = 0.f;
  }
  unsigned* slots = (unsigned*)(ws + OFF_SLOT);
  if (id < 400) {
    slots[SLOT_DMAX + id] = fkey(-INFINITY);
    slots[SLOT_DMIN + id] = fkey(INFINITY);
  }
}

__global__ __launch_bounds__(256) void setup_cb(float* __restrict__ ws) {
  int b = blockIdx.x;
  const float* lap = ws + OFF_LA + b * NPOS;
  float m = -INFINITY;
  for (int i = threadIdx.x; i < NPOS; i += 256) m = fmaxf(m, lap[i]);
#pragma unroll
  for (int o = 1; o < 64; o <<= 1) m = fmaxf(m, __shfl_xor(m, o, 64));
  __shared__ float r[4];
  if ((threadIdx.x & 63) == 0) r[threadIdx.x >> 6] = m;
  __syncthreads();
  if (threadIdx.x == 0)
    ws[OFF_CB + b] = fmaxf(fmaxf(r[0], r[1]), fmaxf(r[2], r[3]));
}

__global__ __launch_bounds__(256) void setup_eu(float* __restrict__ ws) {
  int id = blockIdx.x * 256 + threadIdx.x;        // grid 256 -> 65536
  int b = id >> 13, i = id & (NPOS - 1);
  float la = ws[OFF_LA + id];
  float cb = ws[OFF_CB + b];
  ws[OFF_EU + (size_t)b * EUW + i + PADJ] = expf(la - cb);
}

// ---- conv: one wave per (i-block/256, chunk-of-64-j) task ----
// lane owns i = i0+4*lane+t (t=0..3); per-lane w window = 68 consecutive floats
// (17 coalesced float4); eu read at wave-uniform addresses (scalar pipe).
// partials: part[c][b][i], no cross-lane reduction needed.
__global__ __launch_bounds__(64) void conv_k(
    const float* __restrict__ w2, const float* __restrict__ eu,
    float* __restrict__ part, const unsigned* __restrict__ slots, int k)
{
  if (!run_iter(slots, k)) return;
  const int bid = blockIdx.x;          // 0..2559
  const int ib  = bid / NCH;           // i-block 0..31
  const int c   = bid - ib * NCH;      // chunk 0..79
  const int i0  = ib << 8;
  const int lane = threadIdx.x;        // block = 64 threads = 1 wave
  // eu base (j' index) for this chunk: j' = j + PADJ, j0 = i0 - PADJ + 64c
  const int j0p = __builtin_amdgcn_readfirstlane(i0 + (c << 6));

  // per-lane w window: floats w2[wb .. wb+67], wb = 4*lane + 10560 - 64c (mult of 4)
  float Wf[68];
  {
    const float4* wp = (const float4*)(w2 + ((lane << 2) + 10560 - (c << 6)));
#pragma unroll
    for (int q = 0; q < 17; ++q) {
      float4 v = wp[q];
      Wf[4*q+0] = v.x; Wf[4*q+1] = v.y; Wf[4*q+2] = v.z; Wf[4*q+3] = v.w;
    }
  }

  float acc[4][8];                     // acc[t][b]
#pragma unroll
  for (int t = 0; t < 4; ++t)
#pragma unroll
    for (int b = 0; b < 8; ++b) acc[t][b] = 0.f;

#pragma unroll
  for (int g = 0; g < 16; ++g) {       // 16 groups of 4 j
    float4 e[8];
#pragma unroll
    for (int b = 0; b < 8; ++b)
      e[b] = *(const float4*)(eu + (size_t)b * EUW + j0p + (g << 2));
#pragma unroll
    for (int jj4 = 0; jj4 < 4; ++jj4) {
#pragma unroll
      for (int t = 0; t < 4; ++t) {
        float wv = Wf[63 + t - (g << 2) - jj4];   // static index after unroll
#pragma unroll
        for (int b = 0; b < 8; ++b)
          acc[t][b] = fmaf(wv, EC(e[b], jj4), acc[t][b]);
      }
    }
  }

  // store: 8 coalesced float4 per lane
  float4* p4 = (float4*)part;
  const int ibase = (i0 >> 2) + lane;
#pragma unroll
  for (int b = 0; b < 8; ++b) {
    float4 o;
    o.x = acc[0][b]; o.y = acc[1][b]; o.z = acc[2][b]; o.w = acc[3][b];
    p4[(((size_t)c * 8 + b) << 11) + ibase] = o;
  }
}

// ---- reduce: sum partials, g, f update, eu' write, gap atomics ----
__global__ __launch_bounds__(256) void reduce_k(
    float* __restrict__ ws, const float* __restrict__ part,
    float* __restrict__ eunext, int k)
{
  unsigned* slots = (unsigned*)(ws + OFF_SLOT);
  if (!run_iter(slots, k)) return;
  const int bid = blockIdx.x;                  // 64 blocks
  const int b   = bid >> 3;
  const int i4  = ((bid & 7) << 8) + threadIdx.x;    // 0..2047
  const float4* p4 = (const float4*)part + (((size_t)b) << 11) + i4;

  float sx = 0.f, sy = 0.f, sz = 0.f, sw = 0.f;
#pragma unroll 10
  for (int c = 0; c < NCH; ++c) {
    float4 a = p4[(size_t)c << 14];
    sx += a.x; sy += a.y; sz += a.z; sw += a.w;
  }

  const int i = i4 << 2;
  const float cb = ws[OFF_CB + b];
  float4 laq = *(const float4*)(ws + OFF_LA + b * NPOS + i);
  float* fp  = ws + OFF_F + b * NPOS + i;
  float4 fq  = *(const float4*)fp;

  float v[4] = {sx, sy, sz, sw};
  float lav[4] = {laq.x, laq.y, laq.z, laq.w};
  float fo[4] = {fq.x, fq.y, fq.z, fq.w};
  float fn[4], eo[4];
  float dmax = -INFINITY, dmin = INFINITY;
#pragma unroll
  for (int t = 0; t < 4; ++t) {
    float g = -2.f * (logf(v[t]) + cb);
    float d = fo[t] - g;
    fn[t] = 0.5f * (fo[t] + g);
    float un = 0.5f * fn[t] + lav[t];
    eo[t] = expf(un - cb);
    dmax = fmaxf(dmax, d); dmin = fminf(dmin, d);
  }
  float4 fs; fs.x = fn[0]; fs.y = fn[1]; fs.z = fn[2]; fs.w = fn[3];
  *(float4*)fp = fs;
  float4 es; es.x = eo[0]; es.y = eo[1]; es.z = eo[2]; es.w = eo[3];
  *(float4*)(eunext + (size_t)b * EUW + i + PADJ) = es;

#pragma unroll
  for (int o = 1; o < 64; o <<= 1) {
    dmax = fmaxf(dmax, __shfl_xor(dmax, o, 64));
    dmin = fminf(dmin, __shfl_xor(dmin, o, 64));
  }
  __shared__ float r1[4], r2[4];
  const int wid = threadIdx.x >> 6;
  if ((threadIdx.x & 63) == 0) { r1[wid] = dmax; r2[wid] = dmin; }
  __syncthreads();
  if (threadIdx.x == 0) {
    dmax = fmaxf(fmaxf(r1[0], r1[1]), fmaxf(r1[2], r1[3]));
    dmin = fminf(fminf(r2[0], r2[1]), fminf(r2[2], r2[3]));
    atomicMax(&slots[SLOT_DMAX + k * 8 + b], fkey(dmax));
    atomicMin(&slots[SLOT_DMIN + k * 8 + b], fkey(dmin));
  }
}

__global__ __launch_bounds__(256) void value_k(const float* __restrict__ alpha,
                                               const float* __restrict__ ws,
                                               float* __restrict__ out) {
  int b = blockIdx.x;
  const float* fp = ws + OFF_F + b * NPOS;
  const float* ap = alpha + b * NPOS;
  float s = 0.f;
  for (int i = threadIdx.x; i < NPOS; i += 256) s = fmaf(fp[i], ap[i], s);
#pragma unroll
  for (int o = 1; o < 64; o <<= 1) s += __shfl_xor(s, o, 64);
  __shared__ float red[4];
  if ((threadIdx.x & 63) == 0) red[threadIdx.x >> 6] = s;
  __syncthreads();
  if (threadIdx.x == 0) out[b] = -(red[0] + red[1] + red[2] + red[3]);
}

extern "C" void kernel_launch(void* const* d_in, const int* in_sizes, int n_in,
                              void* d_out, int out_size, void* d_ws, size_t ws_size,
                              hipStream_t stream) {
  const float* alpha = (const float*)d_in[0];
  const float* kern  = (const float*)d_in[1];
  float* ws  = (float*)d_ws;
  float* out = (float*)d_out;

  float* w2p = ws + OFF_W2;
  float* partp = ws + OFF_PART;
  unsigned* slots = (unsigned*)(ws + OFF_SLOT);

  setup_a<<<816, 256, 0, stream>>>(alpha, kern, ws);
  setup_cb<<<8, 256, 0, stream>>>(ws);
  setup_eu<<<256, 256, 0, stream>>>(ws);
  for (int k = 0; k < MAXIT; ++k) {
    float* ecur = ws + OFF_EU + (size_t)(k & 1) * EUSZ;
    float* enxt = ws + OFF_EU + (size_t)((k + 1) & 1) * EUSZ;
    conv_k<<<2560, 64, 0, stream>>>(w2p, ecur, partp, slots, k);
    reduce_k<<<64, 256, 0, stream>>>(ws, partp, enxt, k);
  }
  value_k<<<8, 256, 0, stream>>>(alpha, ws, out);
}

// Round 5
// 1253.373 us; speedup vs baseline: 1.2977x; 1.0662x over previous
//
#include <hip/hip_runtime.h>
#include <math.h>

#define NPOS 8192
#define MAXIT 50
#define TOLF 1e-9f
#define PADJ 2432            // window radius; w(2432)=2.2e-8 -> truncation ~1e-7 rel
#define EUW  13056           // 8192 + 2*2432
#define EUSZ (EUW * 8)       // 104448 floats per eu buffer (8 scalar planes [b][j'])
#define NSL  16              // j-slices per 256-i tile (320 j each; window 5120)

// ws layout (float offsets)
#define OFF_W2   0           // 16384: w2[d+8191] = exp(K(|d|))
#define OFF_LA   16384       // 65536: log(alpha)
#define OFF_F    81920       // 65536: potential f
#define OFF_CB   147456      // 8: fixed per-batch stabilizer cb = max(la)
#define OFF_SLOT 147464      // 800 uints: gap slots
#define OFF_EU   148480      // 2 * 104448: eu double buffer
#define OFF_PART 357376      // 16*8*8192 = 1048576 partial sums (~5.6 MB total ws)

#define SLOT_DMAX 0          // 50*8
#define SLOT_DMIN 400        // 50*8

// static float4 component select (folds at compile time under #pragma unroll)
#define EC(v,kk) ((kk)==0?(v).x:(kk)==1?(v).y:(kk)==2?(v).z:(v).w)

__device__ inline unsigned fkey(float x) {
  unsigned b = __float_as_uint(x);
  return (b & 0x80000000u) ? ~b : (b | 0x80000000u);
}
__device__ inline float fval(unsigned k) {
  unsigned b = (k & 0x80000000u) ? (k ^ 0x80000000u) : ~k;
  return __uint_as_float(b);
}

// run body k iff gap_{k-1} >= TOL (never-run slots -> -inf -> stay stopped)
__device__ inline bool run_iter(const unsigned* slots, int k) {
  if (k == 0) return true;
  const unsigned* dmax = slots + SLOT_DMAX + (k - 1) * 8;
  const unsigned* dmin = slots + SLOT_DMIN + (k - 1) * 8;
  float s = 0.f;
#pragma unroll
  for (int b = 0; b < 8; ++b) s += fval(dmax[b]) - fval(dmin[b]);
  return (s * 0.125f) >= TOLF;
}

__global__ __launch_bounds__(256) void setup_a(const float* __restrict__ alpha,
                                               const float* __restrict__ kern,
                                               float* __restrict__ ws) {
  int id = blockIdx.x * 256 + threadIdx.x;        // grid 816 -> 208896 threads
  ws[OFF_EU + id] = 0.f;                          // zero both eu buffers (2*104448)
  if (id < 16384) {
    int d = id - 8191; if (d < 0) d = -d; if (d > 8191) d = 8191;
    ws[OFF_W2 + id] = expf(kern[d]);              // kernel row 0; Toeplitz-exact
  }
  if (id < 65536) {
    float a = alpha[id];
    ws[OFF_LA + id] = (a > 0.f) ? logf(a) : -INFINITY;
    ws[OFF_F + id] = 0.f;
  }
  unsigned* slots = (unsigned*)(ws + OFF_SLOT);
  if (id < 400) {
    slots[SLOT_DMAX + id] = fkey(-INFINITY);
    slots[SLOT_DMIN + id] = fkey(INFINITY);
  }
}

__global__ __launch_bounds__(256) void setup_cb(float* __restrict__ ws) {
  int b = blockIdx.x;
  const float* lap = ws + OFF_LA + b * NPOS;
  float m = -INFINITY;
  for (int i = threadIdx.x; i < NPOS; i += 256) m = fmaxf(m, lap[i]);
#pragma unroll
  for (int o = 1; o < 64; o <<= 1) m = fmaxf(m, __shfl_xor(m, o, 64));
  __shared__ float r[4];
  if ((threadIdx.x & 63) == 0) r[threadIdx.x >> 6] = m;
  __syncthreads();
  if (threadIdx.x == 0)
    ws[OFF_CB + b] = fmaxf(fmaxf(r[0], r[1]), fmaxf(r[2], r[3]));
}

__global__ __launch_bounds__(256) void setup_eu(float* __restrict__ ws) {
  int id = blockIdx.x * 256 + threadIdx.x;        // grid 256 -> 65536
  int b = id >> 13, i = id & (NPOS - 1);
  float la = ws[OFF_LA + id];
  float cb = ws[OFF_CB + b];
  ws[OFF_EU + (size_t)b * EUW + i + PADJ] = expf(la - cb);
}

// ---- conv: block (i-tile of 256, j-slice of 320) x all 8 batches ----
// 4 waves split the slice into 80-j sub-slices (2 chunks of 40 j each).
// lane owns i = i0 + 4*lane + t. Register acc[4][8]; LDS cross-wave reduce;
// one partial slice written per block: part[js][b][i].
__global__ __launch_bounds__(256, 2) void conv_k(
    const float* __restrict__ w2, const float* __restrict__ eu,
    float* __restrict__ part, const unsigned* __restrict__ slots, int k)
{
  if (!run_iter(slots, k)) return;
  const int it = blockIdx.x >> 4;      // i-tile 0..31
  const int js = blockIdx.x & 15;      // j-slice 0..15
  const int i0 = it << 8;
  const int lane = threadIdx.x & 63;
  const int wid  = threadIdx.x >> 6;

  float acc[4][8];                     // acc[t][b]
#pragma unroll
  for (int t = 0; t < 4; ++t)
#pragma unroll
    for (int b = 0; b < 8; ++b) acc[t][b] = 0.f;

#pragma unroll
  for (int c = 0; c < 2; ++c) {
    // jbase = i0 - 2432 + 320*js + 80*wid + 40*c ; j' base = jbase + PADJ
    const int jp0 = i0 + 320 * js + 80 * wid + 40 * c;        // j' of jj=0
    // per-lane w window: w2[wb .. wb+43], Wf[39 + t - jj]
    const int wb = (lane << 2) + 10584 - 320 * js - 80 * wid - 40 * c;
    float Wf[44];
    {
      const float4* wp = (const float4*)(w2 + wb);
#pragma unroll
      for (int q = 0; q < 11; ++q) {
        float4 v = wp[q];
        Wf[4*q+0] = v.x; Wf[4*q+1] = v.y; Wf[4*q+2] = v.z; Wf[4*q+3] = v.w;
      }
    }
#pragma unroll
    for (int g = 0; g < 10; ++g) {     // 10 groups of 4 j
      float4 E[8];
#pragma unroll
      for (int b = 0; b < 8; ++b)
        E[b] = *(const float4*)(eu + (size_t)b * EUW + jp0 + (g << 2));
#pragma unroll
      for (int e = 0; e < 4; ++e) {
#pragma unroll
        for (int t = 0; t < 4; ++t) {
          float wv = Wf[39 + t - (g << 2) - e];   // static index after unroll
#pragma unroll
          for (int b = 0; b < 8; ++b)
            acc[t][b] = fmaf(wv, EC(E[b], e), acc[t][b]);
        }
      }
    }
  }

  // cross-wave reduce via LDS: lds[w][b][i4] float4 over t
  __shared__ float4 lds[4][8][64];     // 32 KB
#pragma unroll
  for (int b = 0; b < 8; ++b) {
    float4 v; v.x = acc[0][b]; v.y = acc[1][b]; v.z = acc[2][b]; v.w = acc[3][b];
    lds[wid][b][lane] = v;
  }
  __syncthreads();

  // 256 threads: i4 = tid&63, b = tid>>6 and b+4; sum 4 waves; store slice
  const int i4 = threadIdx.x & 63;
  const int b0 = threadIdx.x >> 6;
  float4* p4 = (float4*)part;
#pragma unroll
  for (int h = 0; h < 2; ++h) {
    const int b = b0 + 4 * h;
    float4 s0 = lds[0][b][i4], s1 = lds[1][b][i4];
    float4 s2 = lds[2][b][i4], s3 = lds[3][b][i4];
    float4 o;
    o.x = (s0.x + s1.x) + (s2.x + s3.x);
    o.y = (s0.y + s1.y) + (s2.y + s3.y);
    o.z = (s0.z + s1.z) + (s2.z + s3.z);
    o.w = (s0.w + s1.w) + (s2.w + s3.w);
    p4[(((size_t)js * 8 + b) << 11) + (i0 >> 2) + i4] = o;
  }
}

// ---- reduce: block (b, i-tile of 256); sum 16 slices, fused epilogue ----
__global__ __launch_bounds__(256) void reduce_k(
    float* __restrict__ ws, const float* __restrict__ part,
    float* __restrict__ eunext, int k)
{
  unsigned* slots = (unsigned*)(ws + OFF_SLOT);
  if (!run_iter(slots, k)) return;
  const int b  = blockIdx.x >> 5;
  const int i  = ((blockIdx.x & 31) << 8) + threadIdx.x;

  float v = 0.f;
#pragma unroll
  for (int js = 0; js < NSL; ++js)
    v += part[(((size_t)js * 8 + b) << 13) + i];

  const float cb = ws[OFF_CB + b];
  float g = -2.f * (logf(v) + cb);
  float* fp = ws + OFF_F + b * NPOS;
  float fo = fp[i];
  float d  = fo - g;
  float fn = 0.5f * (fo + g);
  fp[i] = fn;
  float un = 0.5f * fn + ws[OFF_LA + b * NPOS + i];
  eunext[(size_t)b * EUW + i + PADJ] = expf(un - cb);

  float dmax = d, dmin = d;
#pragma unroll
  for (int o = 1; o < 64; o <<= 1) {
    dmax = fmaxf(dmax, __shfl_xor(dmax, o, 64));
    dmin = fminf(dmin, __shfl_xor(dmin, o, 64));
  }
  __shared__ float r1[4], r2[4];
  const int wid = threadIdx.x >> 6;
  if ((threadIdx.x & 63) == 0) { r1[wid] = dmax; r2[wid] = dmin; }
  __syncthreads();
  if (threadIdx.x == 0) {
    dmax = fmaxf(fmaxf(r1[0], r1[1]), fmaxf(r1[2], r1[3]));
    dmin = fminf(fminf(r2[0], r2[1]), fminf(r2[2], r2[3]));
    atomicMax(&slots[SLOT_DMAX + k * 8 + b], fkey(dmax));
    atomicMin(&slots[SLOT_DMIN + k * 8 + b], fkey(dmin));
  }
}

__global__ __launch_bounds__(256) void value_k(const float* __restrict__ alpha,
                                               const float* __restrict__ ws,
                                               float* __restrict__ out) {
  int b = blockIdx.x;
  const float* fp = ws + OFF_F + b * NPOS;
  const float* ap = alpha + b * NPOS;
  float s = 0.f;
  for (int i = threadIdx.x; i < NPOS; i += 256) s = fmaf(fp[i], ap[i], s);
#pragma unroll
  for (int o = 1; o < 64; o <<= 1) s += __shfl_xor(s, o, 64);
  __shared__ float red[4];
  if ((threadIdx.x & 63) == 0) red[threadIdx.x >> 6] = s;
  __syncthreads();
  if (threadIdx.x == 0) out[b] = -(red[0] + red[1] + red[2] + red[3]);
}

extern "C" void kernel_launch(void* const* d_in, const int* in_sizes, int n_in,
                              void* d_out, int out_size, void* d_ws, size_t ws_size,
                              hipStream_t stream) {
  const float* alpha = (const float*)d_in[0];
  const float* kern  = (const float*)d_in[1];
  float* ws  = (float*)d_ws;
  float* out = (float*)d_out;

  float* w2p = ws + OFF_W2;
  float* partp = ws + OFF_PART;
  unsigned* slots = (unsigned*)(ws + OFF_SLOT);

  setup_a<<<816, 256, 0, stream>>>(alpha, kern, ws);
  setup_cb<<<8, 256, 0, stream>>>(ws);
  setup_eu<<<256, 256, 0, stream>>>(ws);
  for (int k = 0; k < MAXIT; ++k) {
    float* ecur = ws + OFF_EU + (size_t)(k & 1) * EUSZ;
    float* enxt = ws + OFF_EU + (size_t)((k + 1) & 1) * EUSZ;
    conv_k<<<512, 256, 0, stream>>>(w2p, ecur, partp, slots, k);
    reduce_k<<<256, 256, 0, stream>>>(ws, partp, enxt, k);
  }
  value_k<<<8, 256, 0, stream>>>(alpha, ws, out);
}

// Round 6
// 1180.416 us; speedup vs baseline: 1.3779x; 1.0618x over previous
//
#include <hip/hip_runtime.h>
#include <math.h>

#define NPOS 8192
#define MAXIT 50
#define TOLF 1e-9f
#define PADJ 2560            // effective radius >= 2552 for every i; w(2552)=3.7e-9
#define EUW  13312           // 8192 + 2*2560
#define EUSZ (EUW * 8)       // 106496 floats per eu buffer (8 scalar planes [b][j'])

// ws layout (float offsets)
#define OFF_W2   0           // 16384: w2[d+8191] = exp(K(|d|))
#define OFF_LA   16384       // 65536: log(alpha)
#define OFF_F    81920       // 65536: potential f
#define OFF_CB   147456      // 8: fixed per-batch stabilizer cb = max(la)
#define OFF_SLOT 147464      // 800 uints: gap slots
#define OFF_EU   148480      // 2 * 106496: eu double buffer (~1.5 MB total ws)

#define SLOT_DMAX 0          // 50*8
#define SLOT_DMIN 400        // 50*8

// static float4 component select (folds at compile time under #pragma unroll)
#define EC(v,kk) ((kk)==0?(v).x:(kk)==1?(v).y:(kk)==2?(v).z:(v).w)

__device__ inline unsigned fkey(float x) {
  unsigned b = __float_as_uint(x);
  return (b & 0x80000000u) ? ~b : (b | 0x80000000u);
}
__device__ inline float fval(unsigned k) {
  unsigned b = (k & 0x80000000u) ? (k ^ 0x80000000u) : ~k;
  return __uint_as_float(b);
}

// run body k iff gap_{k-1} >= TOL (never-run slots -> -inf -> stay stopped)
__device__ inline bool run_iter(const unsigned* slots, int k) {
  if (k == 0) return true;
  const unsigned* dmax = slots + SLOT_DMAX + (k - 1) * 8;
  const unsigned* dmin = slots + SLOT_DMIN + (k - 1) * 8;
  float s = 0.f;
#pragma unroll
  for (int b = 0; b < 8; ++b) s += fval(dmax[b]) - fval(dmin[b]);
  return (s * 0.125f) >= TOLF;
}

__global__ __launch_bounds__(256) void setup_a(const float* __restrict__ alpha,
                                               const float* __restrict__ kern,
                                               float* __restrict__ ws) {
  int id = blockIdx.x * 256 + threadIdx.x;        // grid 832 -> 212992 threads
  ws[OFF_EU + id] = 0.f;                          // zero both eu buffers (2*106496)
  if (id < 16384) {
    int d = id - 8191; if (d < 0) d = -d; if (d > 8191) d = 8191;
    ws[OFF_W2 + id] = expf(kern[d]);              // kernel row 0; Toeplitz-exact
  }
  if (id < 65536) {
    float a = alpha[id];
    ws[OFF_LA + id] = (a > 0.f) ? logf(a) : -INFINITY;
    ws[OFF_F + id] = 0.f;
  }
  unsigned* slots = (unsigned*)(ws + OFF_SLOT);
  if (id < 400) {
    slots[SLOT_DMAX + id] = fkey(-INFINITY);
    slots[SLOT_DMIN + id] = fkey(INFINITY);
  }
}

__global__ __launch_bounds__(256) void setup_cb(float* __restrict__ ws) {
  int b = blockIdx.x;
  const float* lap = ws + OFF_LA + b * NPOS;
  float m = -INFINITY;
  for (int i = threadIdx.x; i < NPOS; i += 256) m = fmaxf(m, lap[i]);
#pragma unroll
  for (int o = 1; o < 64; o <<= 1) m = fmaxf(m, __shfl_xor(m, o, 64));
  __shared__ float r[4];
  if ((threadIdx.x & 63) == 0) r[threadIdx.x >> 6] = m;
  __syncthreads();
  if (threadIdx.x == 0)
    ws[OFF_CB + b] = fmaxf(fmaxf(r[0], r[1]), fmaxf(r[2], r[3]));
}

__global__ __launch_bounds__(256) void setup_eu(float* __restrict__ ws) {
  int id = blockIdx.x * 256 + threadIdx.x;        // grid 256 -> 65536
  int b = id >> 13, i = id & (NPOS - 1);
  float la = ws[OFF_LA + id];
  float cb = ws[OFF_CB + b];
  ws[OFF_EU + (size_t)b * EUW + i + PADJ] = expf(la - cb);
}

// ---- fused iteration: block = (i-tile of 16, all 8 b, full 5120-j window) ----
// 4 waves = 2 j-halves (jh) x 2 batch-halves (bhf). lane owns 4 consecutive j
// per 256-j superstep (10 supersteps). acc[bb*16+ii] in regs; register-halving
// shuffle reduce; LDS combine across j-halves; fused epilogue on 128 threads.
__global__ __launch_bounds__(256, 2) void iter_k(
    const float* __restrict__ w2, const float* __restrict__ la,
    float* __restrict__ f, const float* __restrict__ cb,
    unsigned* __restrict__ slots, const float* __restrict__ eu,
    float* __restrict__ eunext, int k)
{
  if (!run_iter(slots, k)) return;
  const int i0 = blockIdx.x << 4;      // grid 512
  const int lane = threadIdx.x & 63;
  const int wid  = threadIdx.x >> 6;
  const int jh  = wid & 1;
  const int bhf = wid >> 1;

  float A[64];                         // A[bb*16+ii]
#pragma unroll
  for (int a = 0; a < 64; ++a) A[a] = 0.f;

  // j' for (s, jj=0): jp0 + 256 s ; j' = i0+8 ... i0+5127 over the block
  const int jp0 = i0 + 8 + jh * 2560 + (lane << 2);
  // w2 index for (ii,jj): G - 256 s - jj + ii, G = 10743 - jh*2560 - 4*lane
  const int G0  = 10743 - jh * 2560 - (lane << 2);
  const float* eu0 = eu + (size_t)(bhf * 4) * EUW + jp0;

#pragma unroll
  for (int s = 0; s < 10; ++s) {
    float4 E[4];
#pragma unroll
    for (int bb = 0; bb < 4; ++bb)
      E[bb] = *(const float4*)(eu0 + (size_t)bb * EUW + (s << 8));
    float Wf[20];                      // w2[G0-256s-3 .. +16]
    {
      const float4* wp = (const float4*)(w2 + (G0 - (s << 8) - 3));
#pragma unroll
      for (int q = 0; q < 5; ++q) {
        float4 v = wp[q];
        Wf[4*q] = v.x; Wf[4*q+1] = v.y; Wf[4*q+2] = v.z; Wf[4*q+3] = v.w;
      }
    }
#pragma unroll
    for (int jj = 0; jj < 4; ++jj) {
#pragma unroll
      for (int ii = 0; ii < 16; ++ii) {
        float wv = Wf[3 + ii - jj];    // static index after unroll
#pragma unroll
        for (int bb = 0; bb < 4; ++bb)
          A[bb * 16 + ii] = fmaf(wv, EC(E[bb], jj), A[bb * 16 + ii]);
      }
    }
  }

  // register-halving cross-lane reduce: lane L ends with full sum of A[L]
#pragma unroll
  for (int r = 0; r < 6; ++r) {
    const int bit = (lane >> r) & 1;
#pragma unroll
    for (int m = 0; m < (32 >> r); ++m) {
      float x = bit ? A[2 * m + 1] : A[2 * m];
      A[m] = x + __shfl_xor(x, 1 << r, 64);
    }
  }
  __shared__ float smem[4][64];
  smem[wid][lane] = A[0];
  __syncthreads();

  const int t = threadIdx.x;
  if (t < 128) {                       // wave 0 -> bhf 0, wave 1 -> bhf 1
    const int bh2 = t >> 6, L = t & 63;
    float v = smem[bh2 << 1][L] + smem[(bh2 << 1) | 1][L];
    const int b = (bh2 << 2) + (L >> 4);
    const int i = i0 + (L & 15);
    float cbb = cb[b];
    float g = -2.f * (logf(v) + cbb);
    float* fp = f + b * NPOS + i;
    float fo = *fp;
    float d  = fo - g;
    float fn = 0.5f * (fo + g);
    *fp = fn;
    float un = 0.5f * fn + la[b * NPOS + i];
    eunext[(size_t)b * EUW + i + PADJ] = expf(un - cbb);
    float dmax = d, dmin = d;
#pragma unroll
    for (int o = 1; o < 16; o <<= 1) { // reduce over the 16 i's of this b
      dmax = fmaxf(dmax, __shfl_xor(dmax, o, 64));
      dmin = fminf(dmin, __shfl_xor(dmin, o, 64));
    }
    if ((L & 15) == 0) {
      atomicMax(&slots[SLOT_DMAX + k * 8 + b], fkey(dmax));
      atomicMin(&slots[SLOT_DMIN + k * 8 + b], fkey(dmin));
    }
  }
}

__global__ __launch_bounds__(256) void value_k(const float* __restrict__ alpha,
                                               const float* __restrict__ ws,
                                               float* __restrict__ out) {
  int b = blockIdx.x;
  const float* fp = ws + OFF_F + b * NPOS;
  const float* ap = alpha + b * NPOS;
  float s = 0.f;
  for (int i = threadIdx.x; i < NPOS; i += 256) s = fmaf(fp[i], ap[i], s);
#pragma unroll
  for (int o = 1; o < 64; o <<= 1) s += __shfl_xor(s, o, 64);
  __shared__ float red[4];
  if ((threadIdx.x & 63) == 0) red[threadIdx.x >> 6] = s;
  __syncthreads();
  if (threadIdx.x == 0) out[b] = -(red[0] + red[1] + red[2] + red[3]);
}

extern "C" void kernel_launch(void* const* d_in, const int* in_sizes, int n_in,
                              void* d_out, int out_size, void* d_ws, size_t ws_size,
                              hipStream_t stream) {
  const float* alpha = (const float*)d_in[0];
  const float* kern  = (const float*)d_in[1];
  float* ws  = (float*)d_ws;
  float* out = (float*)d_out;

  float* w2p = ws + OFF_W2;
  float* lap = ws + OFF_LA;
  float* fp  = ws + OFF_F;
  float* cbp = ws + OFF_CB;
  unsigned* slots = (unsigned*)(ws + OFF_SLOT);

  setup_a<<<832, 256, 0, stream>>>(alpha, kern, ws);
  setup_cb<<<8, 256, 0, stream>>>(ws);
  setup_eu<<<256, 256, 0, stream>>>(ws);
  for (int k = 0; k < MAXIT; ++k) {
    float* ecur = ws + OFF_EU + (size_t)(k & 1) * EUSZ;
    float* enxt = ws + OFF_EU + (size_t)((k + 1) & 1) * EUSZ;
    iter_k<<<512, 256, 0, stream>>>(w2p, lap, fp, cbp, slots, ecur, enxt, k);
  }
  value_k<<<8, 256, 0, stream>>>(alpha, ws, out);
}